// Round 20
// baseline (226.745 us; speedup 1.0000x reference)
//
#include <hip/hip_runtime.h>
#include <cmath>

// LinearAttention round 20.
// vs r19: gemm16s — barrier-free K-loop. Full W tile (128x256 fp16 = 64KB)
// staged once into LDS (swizzled); B-fragments (X) are direct native f16x8
// global loads (4/step, L2/L3-resident). No per-step barriers/vmcnt drains —
// waves free-run and the compiler pipelines loads across the unrolled K-loop.
// Everything else frozen at r19.

#define B 4
#define C 256
#define Hh 128
#define Wd 128
#define HW (Hh*Wd)
#define HEADS 8
#define HD 32
#define OSCALE 256.0f
#define NSP 16

typedef _Float16 half_t;
typedef _Float16 f16x8 __attribute__((ext_vector_type(8)));
typedef float f32x4 __attribute__((ext_vector_type(4)));

__device__ __forceinline__ void gload_lds16(const half_t* g, half_t* l) {
  __builtin_amdgcn_global_load_lds((const __attribute__((address_space(1))) void*)g,
                                   (__attribute__((address_space(3))) void*)l, 16, 0, 0);
}

// ---------------- all weights fp32 -> fp16 + zero Sk, one launch ----------------
__global__ __launch_bounds__(256) void wcvt_all(const float* __restrict__ wq1,
                                                const float* __restrict__ wk1,
                                                const float* __restrict__ wv1,
                                                const float* __restrict__ wout,
                                                half_t* __restrict__ Wh,
                                                half_t* __restrict__ Woh,
                                                float* __restrict__ Sk) {
  int i = blockIdx.x * 256 + threadIdx.x;  // grid 1024 -> 262144
  if (i < 65536) Wh[i] = (half_t)wq1[i];
  else if (i < 131072) Wh[i] = (half_t)wk1[i - 65536];
  else if (i < 196608) Wh[i] = (half_t)wv1[i - 131072];
  else Woh[i - 196608] = (half_t)wout[i - 196608];
  if (i < B * C) Sk[i] = 0.f;
}

// ---------------- channel LayerNorm -> X_h[b][pix][c] fp16 ----------------
__global__ __launch_bounds__(256) void ln2(const float* __restrict__ fmap,
                                           const float* __restrict__ g,
                                           half_t* __restrict__ Xh) {
  int b = blockIdx.y;
  int lane = threadIdx.x & 63;
  int gq = threadIdx.x >> 6;               // 0..3 channel group
  int px = blockIdx.x * 64 + lane;
  __shared__ float gs[C];
  __shared__ float sm1[4][64], sm2[4][64];
  gs[threadIdx.x] = g[threadIdx.x];
  const float* fp = fmap + ((size_t)b * C + gq * 64) * HW + px;
  float vbuf[64];
  float s = 0.f, s2 = 0.f;
#pragma unroll
  for (int j = 0; j < 64; ++j) {
    float v = fp[(size_t)j * HW];
    vbuf[j] = v;
    s += v; s2 = fmaf(v, v, s2);
  }
  sm1[gq][lane] = s; sm2[gq][lane] = s2;
  __syncthreads();
  float st = 0.f, st2 = 0.f;
#pragma unroll
  for (int q = 0; q < 4; ++q) { st += sm1[q][lane]; st2 += sm2[q][lane]; }
  float mean = st * (1.f / C);
  float var = st2 * (1.f / C) - mean * mean;
  float rstd = rsqrtf(var + 1e-5f);
  half_t* xp = Xh + ((size_t)b * HW + px) * 256 + gq * 64;
#pragma unroll
  for (int j0 = 0; j0 < 64; j0 += 8) {
    f16x8 v8;
#pragma unroll
    for (int jj = 0; jj < 8; ++jj)
      v8[jj] = (half_t)((vbuf[j0 + jj] - mean) * rstd * gs[gq * 64 + j0 + jj]);
    *(f16x8*)(xp + j0) = v8;
  }
}

// ---------------- fp16 MFMA GEMM: W-resident LDS, barrier-free K-loop ----------------
// Y[m][pix] = sum_c W[m][c] X[pix][c]. Tile 128m x 128px, 8 waves (4m x 2px).
// LDS: W tile [128 m][256 c], 16B-chunk XOR swizzle (chunk ^= m&7).
// A-frag from LDS (2-way conflict = free); B-frag = direct f16x8 global load.
__global__ __launch_bounds__(512) void gemm16s(const half_t* __restrict__ Xh,
                                               const half_t* __restrict__ Wh,
                                               half_t* __restrict__ Yh) {
  __shared__ __align__(16) char smem[65536];       // W tile, later out tile
  const int tid = threadIdx.x;
  const int wave = tid >> 6, lane = tid & 63;
  const int lr = lane & 15, lq = lane >> 4;
  const int b = blockIdx.z;
  const int pix0 = blockIdx.x * 128;
  const int m0 = blockIdx.y * 128;
  const int wm = wave >> 1, wn = wave & 1;         // 4 m-waves x 2 px-waves

  // stage full W tile once (source pre-swizzled, linear LDS dest — rule #21)
  const half_t* wb = Wh + (size_t)m0 * 256;
#pragma unroll
  for (int it = 0; it < 8; ++it) {
    int e = it * 512 + tid;                        // 4096 chunks = 128 rows x 32
    int m = e >> 5, ch = e & 31;
    int chg = ch ^ (m & 7);
    gload_lds16(wb + (size_t)m * 256 + chg * 8, (half_t*)smem + e * 8);
  }
  __syncthreads();                                 // single barrier before K-loop

  const half_t* xb = Xh + ((size_t)b * HW + pix0 + wn * 64 + lr) * 256 + lq * 8;

  f32x4 acc[2][4];
#pragma unroll
  for (int i = 0; i < 2; ++i)
#pragma unroll
    for (int j = 0; j < 4; ++j) { f32x4 z = {0.f, 0.f, 0.f, 0.f}; acc[i][j] = z; }

#pragma unroll
  for (int ks = 0; ks < 8; ++ks) {                 // NO barriers — waves free-run
    f16x8 bfr[4];
#pragma unroll
    for (int nf = 0; nf < 4; ++nf)
      bfr[nf] = *(const f16x8*)(xb + (size_t)(nf * 16) * 256 + ks * 32);
    f16x8 afr[2];
#pragma unroll
    for (int mf = 0; mf < 2; ++mf) {
      int m = wm * 32 + mf * 16 + lr;
      int ch = (ks * 4 + lq) ^ (m & 7);
      afr[mf] = *(const f16x8*)(smem + m * 512 + ch * 16);
    }
#pragma unroll
    for (int mf = 0; mf < 2; ++mf)
#pragma unroll
      for (int nf = 0; nf < 4; ++nf)
        acc[mf][nf] = __builtin_amdgcn_mfma_f32_16x16x32_f16(afr[mf], bfr[nf], acc[mf][nf], 0, 0, 0);
  }
  __syncthreads();                                 // all waves done reading W LDS

  // epilogue via swizzled LDS tile -> 256B row bursts
#pragma unroll
  for (int mf = 0; mf < 2; ++mf)
#pragma unroll
    for (int nf = 0; nf < 4; ++nf)
#pragma unroll
      for (int j = 0; j < 4; ++j) {
        int row = wm * 32 + mf * 16 + lq * 4 + j;
        int col = wn * 64 + nf * 16 + lr;
        int byte = row * 256 + ((col * 2) ^ ((row & 7) << 4));
        *(half_t*)(smem + byte) = (half_t)acc[mf][nf][j];
      }
  __syncthreads();
  half_t* dst_base = Yh + (size_t)(m0 >> 8) * ((size_t)B * C * HW)
                     + ((size_t)(b * C + (m0 & 255))) * HW + pix0;
#pragma unroll
  for (int it = 0; it < 4; ++it) {
    int i = it * 512 + tid;                 // 2048 chunks = 128 rows x 16
    int row = i >> 4, ch = i & 15;
    int src = row * 256 + ((ch * 16) ^ ((row & 7) << 4));
    *(f16x8*)(dst_base + (size_t)row * HW + ch * 8) = *(const f16x8*)(smem + src);
  }
}

// ---------------- fused depthwise 3x3 (alignbit + shfl halos) for Q, K(exp+sum), V ----------------
__global__ __launch_bounds__(256) void dw3x3_all(const half_t* __restrict__ Yh,
                                                 const float* __restrict__ wq2,
                                                 const float* __restrict__ wk2,
                                                 const float* __restrict__ wv2,
                                                 half_t* __restrict__ Qh,
                                                 half_t* __restrict__ EK,
                                                 half_t* __restrict__ Vh,
                                                 float* __restrict__ Sk) {
  const size_t SZ = (size_t)B * C * HW;
  int ch = blockIdx.y;
  int ten = ch >> 8;                 // 0=Q, 1=K, 2=V
  int c = ch & 255;
  int b = blockIdx.z;
  int r = threadIdx.x >> 4;
  int cg = threadIdx.x & 15;         // col group (8 px)
  int lane = threadIdx.x & 63;
  int j0 = cg * 8;
  int i = blockIdx.x * 16 + r;
  const half_t* plane = Yh + (size_t)ten * SZ + ((size_t)(b * C + c)) * HW;
  const float* W2 = (ten == 0) ? wq2 : (ten == 1) ? wk2 : wv2;
  half_t wh[9];
#pragma unroll
  for (int k = 0; k < 9; ++k) wh[k] = (half_t)W2[c * 9 + k];
  const int lm1 = (lane - 1) & 63, lp1 = (lane + 1) & 63;
  f16x8 acc8 = {0, 0, 0, 0, 0, 0, 0, 0};
#pragma unroll
  for (int dr = 0; dr < 3; ++dr) {
    int ii = i + dr - 1;
    if (ii < 0 || ii >= Hh) continue;
    uint4 d = *(const uint4*)(plane + ii * Wd + j0);
    unsigned haloL = (unsigned)__shfl((int)d.w, lm1);   // prev lane's d3
    unsigned haloR = (unsigned)__shfl((int)d.x, lp1);   // next lane's d0
    if (cg == 0)  haloL = 0;                            // image left edge (SAME pad)
    if (cg == 15) haloR = 0;                            // image right edge
    unsigned m0 = __builtin_amdgcn_alignbit(d.x, haloL, 16);
    unsigned m1 = __builtin_amdgcn_alignbit(d.y, d.x, 16);
    unsigned m2 = __builtin_amdgcn_alignbit(d.z, d.y, 16);
    unsigned m3 = __builtin_amdgcn_alignbit(d.w, d.z, 16);
    unsigned m4 = __builtin_amdgcn_alignbit(haloR, d.w, 16);
    uint4 lshu = {m0, m1, m2, m3};
    uint4 rshu = {m1, m2, m3, m4};
    f16x8 cv  = __builtin_bit_cast(f16x8, d);
    f16x8 lsh = __builtin_bit_cast(f16x8, lshu);
    f16x8 rsh = __builtin_bit_cast(f16x8, rshu);
    acc8 += lsh * wh[dr * 3] + cv * wh[dr * 3 + 1] + rsh * wh[dr * 3 + 2];
  }
  size_t off = ((size_t)(b * C + c)) * HW + i * Wd + j0;
  if (ten == 1) {                    // K: exp + channel sum (fp32 exp)
    f16x8 o8;
    float local = 0.f;
#pragma unroll
    for (int p = 0; p < 8; ++p) {
      float e = expf((float)acc8[p]);  // logits ~N(0,small): no max pass needed
      o8[p] = (half_t)e;
      local += e;
    }
    *(f16x8*)(EK + off) = o8;
    __shared__ float red[256];
    int t = threadIdx.x;
    red[t] = local; __syncthreads();
    for (int st = 128; st > 0; st >>= 1) {
      if (t < st) red[t] += red[t + st];
      __syncthreads();
    }
    if (t == 0) atomicAdd(&Sk[b * C + c], red[0]);
  } else {
    half_t* dst = (ten == 0) ? Qh : Vh;
    *(f16x8*)(dst + off) = acc8;
  }
}

// ---------------- ctx_raw = EK @ V^T per head, pure MFMA ----------------
__global__ __launch_bounds__(256) void ctx_mfma(const half_t* __restrict__ EK,
                                                const half_t* __restrict__ V,
                                                float* __restrict__ part) {
  int bh = blockIdx.x, sp = blockIdx.y;
  int wave = threadIdx.x >> 6, lane = threadIdx.x & 63;
  int lr = lane & 15, lq = lane >> 4;
  const size_t base = (size_t)bh * HD * HW;
  const half_t* ekp = EK + base + (size_t)lr * HW;
  const half_t* vp  = V  + base + (size_t)lr * HW;
  f32x4 a00 = {0.f,0.f,0.f,0.f}, a01 = a00, a10 = a00, a11 = a00;
  const int n0w = sp * 1024 + wave * 256 + lq * 8;
#pragma unroll
  for (int ks = 0; ks < 8; ++ks) {
    int n = n0w + ks * 32;
    f16x8 fa0 = *(const f16x8*)(ekp + n);
    f16x8 fa1 = *(const f16x8*)(ekp + (size_t)16 * HW + n);
    f16x8 fb0 = *(const f16x8*)(vp + n);
    f16x8 fb1 = *(const f16x8*)(vp + (size_t)16 * HW + n);
    a00 = __builtin_amdgcn_mfma_f32_16x16x32_f16(fa0, fb0, a00, 0, 0, 0);
    a01 = __builtin_amdgcn_mfma_f32_16x16x32_f16(fa0, fb1, a01, 0, 0, 0);
    a10 = __builtin_amdgcn_mfma_f32_16x16x32_f16(fa1, fb0, a10, 0, 0, 0);
    a11 = __builtin_amdgcn_mfma_f32_16x16x32_f16(fa1, fb1, a11, 0, 0, 0);
  }
  __shared__ float red[4][1024];
#pragma unroll
  for (int j = 0; j < 4; ++j) {
    int dlo = lq * 4 + j;
    red[wave][(dlo)      * 32 + lr]      = a00[j];
    red[wave][(dlo)      * 32 + 16 + lr] = a01[j];
    red[wave][(dlo + 16) * 32 + lr]      = a10[j];
    red[wave][(dlo + 16) * 32 + 16 + lr] = a11[j];
  }
  __syncthreads();
  float* pp = part + ((size_t)sp * 32 + bh) * 1024;
  for (int idx = threadIdx.x; idx < 1024; idx += 256)
    pp[idx] = red[0][idx] + red[1][idx] + red[2][idx] + red[3][idx];
}

// ---------------- reduce ctx partials, apply 1/S, emit fp16 TRANSPOSED [e][d] ----------------
__global__ __launch_bounds__(256) void ctxred(const float* __restrict__ part,
                                              const float* __restrict__ Sk,
                                              half_t* __restrict__ ctxh) {
  int bh = blockIdx.x;
  int t = threadIdx.x;
  for (int idx = t; idx < 1024; idx += 256) {
    int d = idx >> 5, e = idx & 31;
    float s = 0.f;
#pragma unroll
    for (int sp = 0; sp < NSP; ++sp) s += part[((size_t)sp * 32 + bh) * 1024 + idx];
    ctxh[(size_t)bh * 1024 + e * 32 + d] = (half_t)(s / Sk[bh * HD + d]);
  }
}

// ---------------- attn6b: P@ctx (MFMA) -> SiLU -> LDS O tile -> O@Wout^T -> fp32 out ----------------
__global__ __launch_bounds__(256) void attn6b(const half_t* __restrict__ Qh,
                                              const half_t* __restrict__ ctxh,
                                              const half_t* __restrict__ Woh,
                                              float* __restrict__ outp) {
  const int b = blockIdx.y;
  const int lane = threadIdx.x & 63;
  const int w = threadIdx.x >> 6;
  const int lr = lane & 15, lq = lane >> 4;
  const int px0 = blockIdx.x * 64;
  const int px = px0 + w * 16 + lr;                   // phase-1 A-row pixel
  __shared__ __align__(16) char osm[64 * 512];        // 32KB O tile [px][c] fp16 swizzled

  // ---- phase 1: O = silu(softmax(q) @ ctx) * OSCALE ----
  {
    const int pxl_base = w * 16 + lq * 4;
    const half_t* cb = ctxh + ((size_t)b * HEADS) * 1024;
    f16x8 cf0 = *(const f16x8*)(cb + (lr)      * 32 + lq * 8);
    f16x8 cf1 = *(const f16x8*)(cb + (16 + lr) * 32 + lq * 8);
#pragma unroll
    for (int h = 0; h < HEADS; ++h) {
      f16x8 nf0, nf1;
      if (h < HEADS - 1) {                            // prefetch next head's frags
        const half_t* nb = cb + (size_t)(h + 1) * 1024;
        nf0 = *(const f16x8*)(nb + (lr)      * 32 + lq * 8);
        nf1 = *(const f16x8*)(nb + (16 + lr) * 32 + lq * 8);
      }
      const half_t* qp = Qh + ((size_t)(b * C + h * HD + lq * 8)) * HW + px;
      float ev[8];
      float psum = 0.f;
#pragma unroll
      for (int j = 0; j < 8; ++j) {
        ev[j] = expf((float)qp[(size_t)j * HW]);      // no max pass: logits bounded
        psum += ev[j];
      }
      float s = psum;
      s += __shfl_xor(s, 16, 64);
      s += __shfl_xor(s, 32, 64);
      float inv = 0.1767766952966369f / s;            // 32^-0.5 / s
      f16x8 pa;
#pragma unroll
      for (int j = 0; j < 8; ++j) pa[j] = (half_t)(ev[j] * inv);

      f32x4 z = {0.f, 0.f, 0.f, 0.f};
      f32x4 a0 = __builtin_amdgcn_mfma_f32_16x16x32_f16(pa, cf0, z, 0, 0, 0);
      f32x4 a1 = __builtin_amdgcn_mfma_f32_16x16x32_f16(pa, cf1, z, 0, 0, 0);
#pragma unroll
      for (int eh = 0; eh < 2; ++eh) {
        f32x4 a = eh ? a1 : a0;
        int cc = h * 32 + eh * 16 + lr;
#pragma unroll
        for (int j = 0; j < 4; ++j) {
          int pxl = pxl_base + j;
          float v = a[j];
          float sg = 1.f / (1.f + expf(-v));
          int byte = pxl * 512 + ((cc * 2) ^ ((pxl & 7) << 4));
          *(half_t*)(osm + byte) = (half_t)(v * sg * OSCALE);
        }
      }
      cf0 = nf0; cf1 = nf1;
    }
  }
  __syncthreads();

  // ---- phase 2: out = O @ Woh^T / OSCALE ----
  f32x4 acc[4][4];
#pragma unroll
  for (int i = 0; i < 4; ++i)
#pragma unroll
    for (int j = 0; j < 4; ++j) { f32x4 z = {0.f, 0.f, 0.f, 0.f}; acc[i][j] = z; }

  const half_t* wbase = Woh + ((size_t)(w * 64 + lr)) * 256 + lq * 8;
#pragma unroll
  for (int k0 = 0; k0 < 256; k0 += 32) {
    f16x8 afr[4], bfr[4];
#pragma unroll
    for (int mf = 0; mf < 4; ++mf)
      afr[mf] = *(const f16x8*)(wbase + (size_t)(mf * 16) * 256 + k0);
#pragma unroll
    for (int nf = 0; nf < 4; ++nf) {
      int r = nf * 16 + lr;
      bfr[nf] = *(const f16x8*)(osm + r * 512 + ((k0 * 2 + lq * 16) ^ ((r & 7) << 4)));
    }
#pragma unroll
    for (int mf = 0; mf < 4; ++mf)
#pragma unroll
      for (int nf = 0; nf < 4; ++nf)
        acc[mf][nf] = __builtin_amdgcn_mfma_f32_16x16x32_f16(afr[mf], bfr[nf], acc[mf][nf], 0, 0, 0);
  }

  // D[row=oc][col=px]; fp32 stores, 16 lanes consecutive px = 64B segments
#pragma unroll
  for (int mf = 0; mf < 4; ++mf) {
    int oc = w * 64 + mf * 16 + lq * 4;
#pragma unroll
    for (int nf = 0; nf < 4; ++nf) {
      float* dst = outp + ((size_t)(b * C + oc)) * HW + px0 + nf * 16 + lr;
#pragma unroll
      for (int j = 0; j < 4; ++j)
        dst[(size_t)j * HW] = acc[mf][nf][j] * (1.0f / OSCALE);
    }
  }
}

extern "C" void kernel_launch(void* const* d_in, const int* in_sizes, int n_in,
                              void* d_out, int out_size, void* d_ws, size_t ws_size,
                              hipStream_t stream) {
  const float* fmap = (const float*)d_in[0];
  const float* g    = (const float*)d_in[1];
  const float* wq1  = (const float*)d_in[2];
  const float* wq2  = (const float*)d_in[3];
  const float* wk1  = (const float*)d_in[4];
  const float* wk2  = (const float*)d_in[5];
  const float* wv1  = (const float*)d_in[6];
  const float* wv2  = (const float*)d_in[7];
  const float* wout = (const float*)d_in[8];
  float* out = (float*)d_out;
  char* ws = (char*)d_ws;

  const size_t SZ = (size_t)B * C * HW;
  const size_t Mi = (size_t)1 << 20;
  // layout (byte offsets), live ranges audited:
  half_t* Xh   = (half_t*)(ws);                  // [0,32Mi)    ln2 -> gemm
  half_t* Yh   = (half_t*)(ws + 32 * Mi);        // [32,128Mi)  Yq|Yk|Yv fp16
  half_t* Qh   = (half_t*)(ws + 128 * Mi);       // [128,160Mi) dw -> attn6b
  half_t* EK   = (half_t*)(ws);                  // [0,32Mi)    exp(k) fp16 (Xh dead)
  half_t* Vh   = (half_t*)out;                   // d_out as fp16 V until attn6b overwrites
  float*  part = (float*)(ws + 96 * Mi);         // [96,98Mi)   over dead Yv (full overwrite)
  float*  Sk   = (float*)(ws + 160 * Mi);        // 4KB — outside all tensor regions
  half_t* ctxh = (half_t*)(ws + 100 * Mi);       // 64KB over dead Yv (full overwrite)
  half_t* Wh   = (half_t*)(ws + 192 * Mi);
  half_t* Woh  = (half_t*)(ws + 192 * Mi + 512 * 1024);

  wcvt_all<<<dim3(1024), 256, 0, stream>>>(wq1, wk1, wv1, wout, Wh, Woh, Sk);

  ln2<<<dim3(HW / 64, B), 256, 0, stream>>>(fmap, g, Xh);

  gemm16s<<<dim3(HW / 128, 6, B), 512, 0, stream>>>(Xh, Wh, Yh);

  dw3x3_all<<<dim3(Hh / 16, 3 * C, B), 256, 0, stream>>>(Yh, wq2, wk2, wv2,
                                                         Qh, EK, Vh, Sk);

  ctx_mfma<<<dim3(HEADS * B, NSP), 256, 0, stream>>>(EK, Vh, part);
  ctxred<<<dim3(32), 256, 0, stream>>>(part, Sk, ctxh);

  attn6b<<<dim3(HW / 64, B), 256, 0, stream>>>(Qh, ctxh, Woh, out);
}

// Round 21
// 169.504 us; speedup vs baseline: 1.3377x; 1.3377x over previous
//
#include <hip/hip_runtime.h>
#include <cmath>

// LinearAttention round 21 — REVERT to r19 (best known: 169.4us).
// r20's gemm16s (W-resident barrier-free) failed: 1.57M LDS bank conflicts +
// direct-global-B latency serialization (106us). gemm16r (ring-4, counted
// vmcnt, 44us) is the GEMM plateau after six structural variants.

#define B 4
#define C 256
#define Hh 128
#define Wd 128
#define HW (Hh*Wd)
#define HEADS 8
#define HD 32
#define OSCALE 256.0f
#define NSP 16

typedef _Float16 half_t;
typedef _Float16 f16x8 __attribute__((ext_vector_type(8)));
typedef float f32x4 __attribute__((ext_vector_type(4)));

__device__ __forceinline__ void gload_lds16(const half_t* g, half_t* l) {
  __builtin_amdgcn_global_load_lds((const __attribute__((address_space(1))) void*)g,
                                   (__attribute__((address_space(3))) void*)l, 16, 0, 0);
}

// ---------------- all weights fp32 -> fp16 + zero Sk, one launch ----------------
__global__ __launch_bounds__(256) void wcvt_all(const float* __restrict__ wq1,
                                                const float* __restrict__ wk1,
                                                const float* __restrict__ wv1,
                                                const float* __restrict__ wout,
                                                half_t* __restrict__ Wh,
                                                half_t* __restrict__ Woh,
                                                float* __restrict__ Sk) {
  int i = blockIdx.x * 256 + threadIdx.x;  // grid 1024 -> 262144
  if (i < 65536) Wh[i] = (half_t)wq1[i];
  else if (i < 131072) Wh[i] = (half_t)wk1[i - 65536];
  else if (i < 196608) Wh[i] = (half_t)wv1[i - 131072];
  else Woh[i - 196608] = (half_t)wout[i - 196608];
  if (i < B * C) Sk[i] = 0.f;
}

// ---------------- channel LayerNorm -> X_h[b][pix][c] fp16 ----------------
__global__ __launch_bounds__(256) void ln2(const float* __restrict__ fmap,
                                           const float* __restrict__ g,
                                           half_t* __restrict__ Xh) {
  int b = blockIdx.y;
  int lane = threadIdx.x & 63;
  int gq = threadIdx.x >> 6;               // 0..3 channel group
  int px = blockIdx.x * 64 + lane;
  __shared__ float gs[C];
  __shared__ float sm1[4][64], sm2[4][64];
  gs[threadIdx.x] = g[threadIdx.x];
  const float* fp = fmap + ((size_t)b * C + gq * 64) * HW + px;
  float vbuf[64];
  float s = 0.f, s2 = 0.f;
#pragma unroll
  for (int j = 0; j < 64; ++j) {
    float v = fp[(size_t)j * HW];
    vbuf[j] = v;
    s += v; s2 = fmaf(v, v, s2);
  }
  sm1[gq][lane] = s; sm2[gq][lane] = s2;
  __syncthreads();
  float st = 0.f, st2 = 0.f;
#pragma unroll
  for (int q = 0; q < 4; ++q) { st += sm1[q][lane]; st2 += sm2[q][lane]; }
  float mean = st * (1.f / C);
  float var = st2 * (1.f / C) - mean * mean;
  float rstd = rsqrtf(var + 1e-5f);
  half_t* xp = Xh + ((size_t)b * HW + px) * 256 + gq * 64;
#pragma unroll
  for (int j0 = 0; j0 < 64; j0 += 8) {
    f16x8 v8;
#pragma unroll
    for (int jj = 0; jj < 8; ++jj)
      v8[jj] = (half_t)((vbuf[j0 + jj] - mean) * rstd * gs[gq * 64 + j0 + jj]);
    *(f16x8*)(xp + j0) = v8;
  }
}

// ---------------- fp16 MFMA GEMM: BK=32 ring-4, counted vmcnt (r16 proven) ----------------
__global__ __launch_bounds__(512) void gemm16r(const half_t* __restrict__ Xh,
                                               const half_t* __restrict__ Wh,
                                               half_t* __restrict__ Yh) {
  __shared__ __align__(16) char smem[65536];       // 4 ring slots / out tile
  const int tid = threadIdx.x;
  const int wave = tid >> 6, lane = tid & 63;
  const int lr = lane & 15, lq = lane >> 4;
  const int b = blockIdx.z;
  const int pix0 = blockIdx.x * 128;
  const int m0 = blockIdx.y * 128;
  const int wm = wave >> 1, wn = wave & 1;         // 4 m-waves x 2 px-waves

  const half_t* xb = Xh + ((size_t)b * HW + pix0) * 256;
  const half_t* wb = Wh + (size_t)m0 * 256;

  f32x4 acc[2][4];
#pragma unroll
  for (int i = 0; i < 2; ++i)
#pragma unroll
    for (int j = 0; j < 4; ++j) { f32x4 z = {0.f, 0.f, 0.f, 0.f}; acc[i][j] = z; }

#define STAGE(kt, s) do {                                                       \
    int r_ = tid >> 2, c_ = tid & 3;                                            \
    int cs_ = c_ ^ ((r_ >> 1) & 3);                                             \
    gload_lds16(xb + (size_t)r_ * 256 + (kt) * 32 + (cs_ << 3),                 \
                (half_t*)(smem + (s) * 16384) + tid * 8);                       \
    gload_lds16(wb + (size_t)r_ * 256 + (kt) * 32 + (cs_ << 3),                 \
                (half_t*)(smem + (s) * 16384 + 8192) + tid * 8);                \
  } while (0)

  STAGE(0, 0);
  STAGE(1, 1);

#pragma unroll
  for (int t = 0; t < 8; ++t) {
    if (t < 6) STAGE(t + 2, (t + 2) & 3);
    if (t < 6)       asm volatile("s_waitcnt vmcnt(4)" ::: "memory");
    else if (t == 6) asm volatile("s_waitcnt vmcnt(2)" ::: "memory");
    else             asm volatile("s_waitcnt vmcnt(0)" ::: "memory");
    __builtin_amdgcn_sched_barrier(0);
    __builtin_amdgcn_s_barrier();                  // all waves: tile t landed
    const char* slot = smem + (t & 3) * 16384;
    f16x8 afr[2], bfr[4];
#pragma unroll
    for (int mf = 0; mf < 2; ++mf) {
      int r = wm * 32 + mf * 16 + lr;
      afr[mf] = *(const f16x8*)(slot + 8192 + r * 64 + ((lq ^ ((r >> 1) & 3)) << 4));
    }
#pragma unroll
    for (int nf = 0; nf < 4; ++nf) {
      int r = wn * 64 + nf * 16 + lr;
      bfr[nf] = *(const f16x8*)(slot + r * 64 + ((lq ^ ((r >> 1) & 3)) << 4));
    }
#pragma unroll
    for (int mf = 0; mf < 2; ++mf)
#pragma unroll
      for (int nf = 0; nf < 4; ++nf)
        acc[mf][nf] = __builtin_amdgcn_mfma_f32_16x16x32_f16(afr[mf], bfr[nf], acc[mf][nf], 0, 0, 0);
  }
#undef STAGE
  asm volatile("s_waitcnt lgkmcnt(0)" ::: "memory");
  __builtin_amdgcn_sched_barrier(0);
  __builtin_amdgcn_s_barrier();                    // smem free for out tile

  // epilogue via swizzled LDS tile -> 256B row bursts
#pragma unroll
  for (int mf = 0; mf < 2; ++mf)
#pragma unroll
    for (int nf = 0; nf < 4; ++nf)
#pragma unroll
      for (int j = 0; j < 4; ++j) {
        int row = wm * 32 + mf * 16 + lq * 4 + j;
        int col = wn * 64 + nf * 16 + lr;
        int byte = row * 256 + ((col * 2) ^ ((row & 7) << 4));
        *(half_t*)(smem + byte) = (half_t)acc[mf][nf][j];
      }
  __syncthreads();
  half_t* dst_base = Yh + (size_t)(m0 >> 8) * ((size_t)B * C * HW)
                     + ((size_t)(b * C + (m0 & 255))) * HW + pix0;
#pragma unroll
  for (int it = 0; it < 4; ++it) {
    int i = it * 512 + tid;                 // 2048 chunks = 128 rows x 16
    int row = i >> 4, ch = i & 15;
    int src = row * 256 + ((ch * 16) ^ ((row & 7) << 4));
    *(f16x8*)(dst_base + (size_t)row * HW + ch * 8) = *(const f16x8*)(smem + src);
  }
}

// ---------------- fused depthwise 3x3 (alignbit + shfl halos) for Q, K(exp+sum), V ----------------
__global__ __launch_bounds__(256) void dw3x3_all(const half_t* __restrict__ Yh,
                                                 const float* __restrict__ wq2,
                                                 const float* __restrict__ wk2,
                                                 const float* __restrict__ wv2,
                                                 half_t* __restrict__ Qh,
                                                 half_t* __restrict__ EK,
                                                 half_t* __restrict__ Vh,
                                                 float* __restrict__ Sk) {
  const size_t SZ = (size_t)B * C * HW;
  int ch = blockIdx.y;
  int ten = ch >> 8;                 // 0=Q, 1=K, 2=V
  int c = ch & 255;
  int b = blockIdx.z;
  int r = threadIdx.x >> 4;
  int cg = threadIdx.x & 15;         // col group (8 px)
  int lane = threadIdx.x & 63;
  int j0 = cg * 8;
  int i = blockIdx.x * 16 + r;
  const half_t* plane = Yh + (size_t)ten * SZ + ((size_t)(b * C + c)) * HW;
  const float* W2 = (ten == 0) ? wq2 : (ten == 1) ? wk2 : wv2;
  half_t wh[9];
#pragma unroll
  for (int k = 0; k < 9; ++k) wh[k] = (half_t)W2[c * 9 + k];
  const int lm1 = (lane - 1) & 63, lp1 = (lane + 1) & 63;
  f16x8 acc8 = {0, 0, 0, 0, 0, 0, 0, 0};
#pragma unroll
  for (int dr = 0; dr < 3; ++dr) {
    int ii = i + dr - 1;
    if (ii < 0 || ii >= Hh) continue;
    uint4 d = *(const uint4*)(plane + ii * Wd + j0);
    unsigned haloL = (unsigned)__shfl((int)d.w, lm1);   // prev lane's d3
    unsigned haloR = (unsigned)__shfl((int)d.x, lp1);   // next lane's d0
    if (cg == 0)  haloL = 0;                            // image left edge (SAME pad)
    if (cg == 15) haloR = 0;                            // image right edge
    unsigned m0 = __builtin_amdgcn_alignbit(d.x, haloL, 16);
    unsigned m1 = __builtin_amdgcn_alignbit(d.y, d.x, 16);
    unsigned m2 = __builtin_amdgcn_alignbit(d.z, d.y, 16);
    unsigned m3 = __builtin_amdgcn_alignbit(d.w, d.z, 16);
    unsigned m4 = __builtin_amdgcn_alignbit(haloR, d.w, 16);
    uint4 lshu = {m0, m1, m2, m3};
    uint4 rshu = {m1, m2, m3, m4};
    f16x8 cv  = __builtin_bit_cast(f16x8, d);
    f16x8 lsh = __builtin_bit_cast(f16x8, lshu);
    f16x8 rsh = __builtin_bit_cast(f16x8, rshu);
    acc8 += lsh * wh[dr * 3] + cv * wh[dr * 3 + 1] + rsh * wh[dr * 3 + 2];
  }
  size_t off = ((size_t)(b * C + c)) * HW + i * Wd + j0;
  if (ten == 1) {                    // K: exp + channel sum (fp32 exp)
    f16x8 o8;
    float local = 0.f;
#pragma unroll
    for (int p = 0; p < 8; ++p) {
      float e = expf((float)acc8[p]);  // logits ~N(0,small): no max pass needed
      o8[p] = (half_t)e;
      local += e;
    }
    *(f16x8*)(EK + off) = o8;
    __shared__ float red[256];
    int t = threadIdx.x;
    red[t] = local; __syncthreads();
    for (int st = 128; st > 0; st >>= 1) {
      if (t < st) red[t] += red[t + st];
      __syncthreads();
    }
    if (t == 0) atomicAdd(&Sk[b * C + c], red[0]);
  } else {
    half_t* dst = (ten == 0) ? Qh : Vh;
    *(f16x8*)(dst + off) = acc8;
  }
}

// ---------------- ctx_raw = EK @ V^T per head, pure MFMA ----------------
__global__ __launch_bounds__(256) void ctx_mfma(const half_t* __restrict__ EK,
                                                const half_t* __restrict__ V,
                                                float* __restrict__ part) {
  int bh = blockIdx.x, sp = blockIdx.y;
  int wave = threadIdx.x >> 6, lane = threadIdx.x & 63;
  int lr = lane & 15, lq = lane >> 4;
  const size_t base = (size_t)bh * HD * HW;
  const half_t* ekp = EK + base + (size_t)lr * HW;
  const half_t* vp  = V  + base + (size_t)lr * HW;
  f32x4 a00 = {0.f,0.f,0.f,0.f}, a01 = a00, a10 = a00, a11 = a00;
  const int n0w = sp * 1024 + wave * 256 + lq * 8;
#pragma unroll
  for (int ks = 0; ks < 8; ++ks) {
    int n = n0w + ks * 32;
    f16x8 fa0 = *(const f16x8*)(ekp + n);
    f16x8 fa1 = *(const f16x8*)(ekp + (size_t)16 * HW + n);
    f16x8 fb0 = *(const f16x8*)(vp + n);
    f16x8 fb1 = *(const f16x8*)(vp + (size_t)16 * HW + n);
    a00 = __builtin_amdgcn_mfma_f32_16x16x32_f16(fa0, fb0, a00, 0, 0, 0);
    a01 = __builtin_amdgcn_mfma_f32_16x16x32_f16(fa0, fb1, a01, 0, 0, 0);
    a10 = __builtin_amdgcn_mfma_f32_16x16x32_f16(fa1, fb0, a10, 0, 0, 0);
    a11 = __builtin_amdgcn_mfma_f32_16x16x32_f16(fa1, fb1, a11, 0, 0, 0);
  }
  __shared__ float red[4][1024];
#pragma unroll
  for (int j = 0; j < 4; ++j) {
    int dlo = lq * 4 + j;
    red[wave][(dlo)      * 32 + lr]      = a00[j];
    red[wave][(dlo)      * 32 + 16 + lr] = a01[j];
    red[wave][(dlo + 16) * 32 + lr]      = a10[j];
    red[wave][(dlo + 16) * 32 + 16 + lr] = a11[j];
  }
  __syncthreads();
  float* pp = part + ((size_t)sp * 32 + bh) * 1024;
  for (int idx = threadIdx.x; idx < 1024; idx += 256)
    pp[idx] = red[0][idx] + red[1][idx] + red[2][idx] + red[3][idx];
}

// ---------------- reduce ctx partials, apply 1/S, emit fp16 TRANSPOSED [e][d] ----------------
__global__ __launch_bounds__(256) void ctxred(const float* __restrict__ part,
                                              const float* __restrict__ Sk,
                                              half_t* __restrict__ ctxh) {
  int bh = blockIdx.x;
  int t = threadIdx.x;
  for (int idx = t; idx < 1024; idx += 256) {
    int d = idx >> 5, e = idx & 31;
    float s = 0.f;
#pragma unroll
    for (int sp = 0; sp < NSP; ++sp) s += part[((size_t)sp * 32 + bh) * 1024 + idx];
    ctxh[(size_t)bh * 1024 + e * 32 + d] = (half_t)(s / Sk[bh * HD + d]);
  }
}

// ---------------- attn6b: P@ctx (MFMA) -> SiLU -> LDS O tile -> O@Wout^T -> fp32 out ----------------
__global__ __launch_bounds__(256) void attn6b(const half_t* __restrict__ Qh,
                                              const half_t* __restrict__ ctxh,
                                              const half_t* __restrict__ Woh,
                                              float* __restrict__ outp) {
  const int b = blockIdx.y;
  const int lane = threadIdx.x & 63;
  const int w = threadIdx.x >> 6;
  const int lr = lane & 15, lq = lane >> 4;
  const int px0 = blockIdx.x * 64;
  const int px = px0 + w * 16 + lr;                   // phase-1 A-row pixel
  __shared__ __align__(16) char osm[64 * 512];        // 32KB O tile [px][c] fp16 swizzled

  // ---- phase 1: O = silu(softmax(q) @ ctx) * OSCALE ----
  {
    const int pxl_base = w * 16 + lq * 4;
    const half_t* cb = ctxh + ((size_t)b * HEADS) * 1024;
    f16x8 cf0 = *(const f16x8*)(cb + (lr)      * 32 + lq * 8);
    f16x8 cf1 = *(const f16x8*)(cb + (16 + lr) * 32 + lq * 8);
#pragma unroll
    for (int h = 0; h < HEADS; ++h) {
      f16x8 nf0, nf1;
      if (h < HEADS - 1) {                            // prefetch next head's frags
        const half_t* nb = cb + (size_t)(h + 1) * 1024;
        nf0 = *(const f16x8*)(nb + (lr)      * 32 + lq * 8);
        nf1 = *(const f16x8*)(nb + (16 + lr) * 32 + lq * 8);
      }
      const half_t* qp = Qh + ((size_t)(b * C + h * HD + lq * 8)) * HW + px;
      float ev[8];
      float psum = 0.f;
#pragma unroll
      for (int j = 0; j < 8; ++j) {
        ev[j] = expf((float)qp[(size_t)j * HW]);      // no max pass: logits bounded
        psum += ev[j];
      }
      float s = psum;
      s += __shfl_xor(s, 16, 64);
      s += __shfl_xor(s, 32, 64);
      float inv = 0.1767766952966369f / s;            // 32^-0.5 / s
      f16x8 pa;
#pragma unroll
      for (int j = 0; j < 8; ++j) pa[j] = (half_t)(ev[j] * inv);

      f32x4 z = {0.f, 0.f, 0.f, 0.f};
      f32x4 a0 = __builtin_amdgcn_mfma_f32_16x16x32_f16(pa, cf0, z, 0, 0, 0);
      f32x4 a1 = __builtin_amdgcn_mfma_f32_16x16x32_f16(pa, cf1, z, 0, 0, 0);
#pragma unroll
      for (int eh = 0; eh < 2; ++eh) {
        f32x4 a = eh ? a1 : a0;
        int cc = h * 32 + eh * 16 + lr;
#pragma unroll
        for (int j = 0; j < 4; ++j) {
          int pxl = pxl_base + j;
          float v = a[j];
          float sg = 1.f / (1.f + expf(-v));
          int byte = pxl * 512 + ((cc * 2) ^ ((pxl & 7) << 4));
          *(half_t*)(osm + byte) = (half_t)(v * sg * OSCALE);
        }
      }
      cf0 = nf0; cf1 = nf1;
    }
  }
  __syncthreads();

  // ---- phase 2: out = O @ Woh^T / OSCALE ----
  f32x4 acc[4][4];
#pragma unroll
  for (int i = 0; i < 4; ++i)
#pragma unroll
    for (int j = 0; j < 4; ++j) { f32x4 z = {0.f, 0.f, 0.f, 0.f}; acc[i][j] = z; }

  const half_t* wbase = Woh + ((size_t)(w * 64 + lr)) * 256 + lq * 8;
#pragma unroll
  for (int k0 = 0; k0 < 256; k0 += 32) {
    f16x8 afr[4], bfr[4];
#pragma unroll
    for (int mf = 0; mf < 4; ++mf)
      afr[mf] = *(const f16x8*)(wbase + (size_t)(mf * 16) * 256 + k0);
#pragma unroll
    for (int nf = 0; nf < 4; ++nf) {
      int r = nf * 16 + lr;
      bfr[nf] = *(const f16x8*)(osm + r * 512 + ((k0 * 2 + lq * 16) ^ ((r & 7) << 4)));
    }
#pragma unroll
    for (int mf = 0; mf < 4; ++mf)
#pragma unroll
      for (int nf = 0; nf < 4; ++nf)
        acc[mf][nf] = __builtin_amdgcn_mfma_f32_16x16x32_f16(afr[mf], bfr[nf], acc[mf][nf], 0, 0, 0);
  }

  // D[row=oc][col=px]; fp32 stores, 16 lanes consecutive px = 64B segments
#pragma unroll
  for (int mf = 0; mf < 4; ++mf) {
    int oc = w * 64 + mf * 16 + lq * 4;
#pragma unroll
    for (int nf = 0; nf < 4; ++nf) {
      float* dst = outp + ((size_t)(b * C + oc)) * HW + px0 + nf * 16 + lr;
#pragma unroll
      for (int j = 0; j < 4; ++j)
        dst[(size_t)j * HW] = acc[mf][nf][j] * (1.0f / OSCALE);
    }
  }
}

extern "C" void kernel_launch(void* const* d_in, const int* in_sizes, int n_in,
                              void* d_out, int out_size, void* d_ws, size_t ws_size,
                              hipStream_t stream) {
  const float* fmap = (const float*)d_in[0];
  const float* g    = (const float*)d_in[1];
  const float* wq1  = (const float*)d_in[2];
  const float* wq2  = (const float*)d_in[3];
  const float* wk1  = (const float*)d_in[4];
  const float* wk2  = (const float*)d_in[5];
  const float* wv1  = (const float*)d_in[6];
  const float* wv2  = (const float*)d_in[7];
  const float* wout = (const float*)d_in[8];
  float* out = (float*)d_out;
  char* ws = (char*)d_ws;

  const size_t SZ = (size_t)B * C * HW;
  const size_t Mi = (size_t)1 << 20;
  // layout (byte offsets), live ranges audited:
  half_t* Xh   = (half_t*)(ws);                  // [0,32Mi)    ln2 -> gemm
  half_t* Yh   = (half_t*)(ws + 32 * Mi);        // [32,128Mi)  Yq|Yk|Yv fp16
  half_t* Qh   = (half_t*)(ws + 128 * Mi);       // [128,160Mi) dw -> attn6b
  half_t* EK   = (half_t*)(ws);                  // [0,32Mi)    exp(k) fp16 (Xh dead)
  half_t* Vh   = (half_t*)out;                   // d_out as fp16 V until attn6b overwrites
  float*  part = (float*)(ws + 96 * Mi);         // [96,98Mi)   over dead Yv (full overwrite)
  float*  Sk   = (float*)(ws + 160 * Mi);        // 4KB — outside all tensor regions
  half_t* ctxh = (half_t*)(ws + 100 * Mi);       // 64KB over dead Yv (full overwrite)
  half_t* Wh   = (half_t*)(ws + 192 * Mi);
  half_t* Woh  = (half_t*)(ws + 192 * Mi + 512 * 1024);

  wcvt_all<<<dim3(1024), 256, 0, stream>>>(wq1, wk1, wv1, wout, Wh, Woh, Sk);

  ln2<<<dim3(HW / 64, B), 256, 0, stream>>>(fmap, g, Xh);

  gemm16r<<<dim3(HW / 128, 6, B), 512, 0, stream>>>(Xh, Wh, Yh);

  dw3x3_all<<<dim3(Hh / 16, 3 * C, B), 256, 0, stream>>>(Yh, wq2, wk2, wv2,
                                                         Qh, EK, Vh, Sk);

  ctx_mfma<<<dim3(HEADS * B, NSP), 256, 0, stream>>>(EK, Vh, part);
  ctxred<<<dim3(32), 256, 0, stream>>>(part, Sk, ctxh);

  attn6b<<<dim3(HW / 64, B), 256, 0, stream>>>(Qh, ctxh, Woh, out);
}